// Round 4
// baseline (913.052 us; speedup 1.0000x reference)
//
#include <hip/hip_runtime.h>

#define NN   100000
#define NE   1600000
#define NT   1700000      // NE + NN self-loops
#define BSH  9            // 512 nodes per bucket
#define BSZ  512
#define NBK  196          // ceil(NN/512)
#define TILE_A 8192
#define NBA  196          // ceil(NE/TILE_A)
#define TILE_H 4096
#define NBH  391          // ceil(NE/TILE_H)
#define CAPB 10240        // LDS staging capacity (entries) in k_binB
#define NBN  391          // ceil(NN/256)

typedef _Float16 half_t;
typedef __attribute__((ext_vector_type(2))) _Float16 f16x2;
typedef __attribute__((ext_vector_type(4))) _Float16 f16x4;
typedef __attribute__((ext_vector_type(8))) _Float16 f16x8;
typedef __attribute__((ext_vector_type(4))) float    f32x4;

// ============================ small utils ============================

__global__ __launch_bounds__(256) void k_zero(int* __restrict__ p, int n) {
  int i = blockIdx.x * 256 + threadIdx.x;
  if (i < n) p[i] = 0;
}

// ============================ bucket histogram ============================
__global__ __launch_bounds__(256) void k_bhist(const int* __restrict__ dst, int* __restrict__ bcnt) {
  __shared__ int h[NBK];
  int t = threadIdx.x;
  for (int i = t; i < NBK; i += 256) h[i] = 0;
  __syncthreads();
  int e0 = blockIdx.x * TILE_H;
#pragma unroll
  for (int i = 0; i < TILE_H / 256; i++) {
    int e = e0 + t + i * 256;
    if (e < NE) atomicAdd(&h[dst[e] >> BSH], 1);
  }
  __syncthreads();
  for (int i = t; i < NBK; i += 256) {
    int c = h[i];
    if (c > 0) atomicAdd(&bcnt[i], c);
  }
}

// scan bucket counts -> ebase (edges only, for bpk) and abase (edges+selfloops, for pk2/offs)
__global__ __launch_bounds__(256) void k_bscan(const int* __restrict__ bcnt, int* __restrict__ ebase,
                                               int* __restrict__ abase, int* __restrict__ bcur,
                                               int* __restrict__ offs) {
  __shared__ int sh[256];
  int t = threadIdx.x;
  int nloc = 0;
  if (t < NBK) {
    int nbeg = t << BSH;
    nloc = min(BSZ, NN - nbeg);
  }
  int ve = (t < NBK) ? bcnt[t] : 0;
  // scan 1: edges only
  {
    int x = ve;
    sh[t] = x;
    for (int off = 1; off < 256; off <<= 1) {
      __syncthreads();
      int y = (t >= off) ? sh[t - off] : 0;
      __syncthreads();
      x += y;
      sh[t] = x;
    }
    if (t < NBK) { ebase[t] = x - ve; bcur[t] = x - ve; }
  }
  __syncthreads();
  // scan 2: edges + self loops
  {
    int va = ve + nloc;
    int x = va;
    sh[t] = x;
    for (int off = 1; off < 256; off <<= 1) {
      __syncthreads();
      int y = (t >= off) ? sh[t - off] : 0;
      __syncthreads();
      x += y;
      sh[t] = x;
    }
    if (t < NBK) abase[t] = x - va;
  }
  if (t == 0) offs[NN] = NT;
}

// ============================ pass A: bin edges by bucket ============================
__global__ __launch_bounds__(256) void k_binA(const int* __restrict__ src, const int* __restrict__ dst,
                                              int* __restrict__ bcur, unsigned int* __restrict__ bpk) {
  __shared__ int hist[NBK];
  __shared__ int hscan[NBK];
  __shared__ int gbase[NBK];
  __shared__ int cnt[NBK];
  __shared__ int ssc[256];
  __shared__ unsigned int staged[TILE_A];
  int t = threadIdx.x;
  int e0 = blockIdx.x * TILE_A;
  for (int i = t; i < NBK; i += 256) { hist[i] = 0; cnt[i] = 0; }
  __syncthreads();
#pragma unroll
  for (int i = 0; i < TILE_A / 256; i++) {
    int e = e0 + t + i * 256;
    if (e < NE) atomicAdd(&hist[dst[e] >> BSH], 1);
  }
  __syncthreads();
  {
    int v = (t < NBK) ? hist[t] : 0;
    int x = v;
    ssc[t] = x;
    for (int off = 1; off < 256; off <<= 1) {
      __syncthreads();
      int y = (t >= off) ? ssc[t - off] : 0;
      __syncthreads();
      x += y;
      ssc[t] = x;
    }
    if (t < NBK) {
      hscan[t] = x - v;
      if (v > 0) gbase[t] = atomicAdd(&bcur[t], v);
    }
  }
  __syncthreads();
#pragma unroll
  for (int i = 0; i < TILE_A / 256; i++) {
    int e = e0 + t + i * 256;
    if (e < NE) {
      int d = dst[e];
      int b = d >> BSH;
      int pos = hscan[b] + atomicAdd(&cnt[b], 1);
      staged[pos] = ((unsigned int)src[e] << BSH) | (unsigned int)(d & (BSZ - 1));
    }
  }
  __syncthreads();
  int wave = t >> 6, lane = t & 63;
  for (int b = wave; b < NBK; b += 4) {
    int c = hist[b];
    if (c > 0) {
      int lo = hscan[b], gb = gbase[b];
      for (int j = lane; j < c; j += 64) bpk[gb + j] = staged[lo + j];
    }
  }
}

// ============================ pass B: sort bucket by dst, add self-loops, emit offs + pk2 ============
__global__ __launch_bounds__(256) void k_binB(const unsigned int* __restrict__ bpk,
                                              const int* __restrict__ bcnt,
                                              const int* __restrict__ ebase,
                                              const int* __restrict__ abase,
                                              int* __restrict__ offs, unsigned int* __restrict__ pk2) {
  __shared__ int lhist[BSZ];
  __shared__ int lscan[BSZ];
  __shared__ int lcur[BSZ];
  __shared__ int ssc[256];
  __shared__ unsigned int staged[CAPB];
  int b = blockIdx.x;
  int t = threadIdx.x;
  int nbeg = b << BSH;
  int nloc = min(BSZ, NN - nbeg);
  int ebeg = ebase[b];
  int ecnt = bcnt[b];
  int aeg = abase[b];
  int total = ecnt + nloc;
  for (int i = t; i < BSZ; i += 256) {
    lhist[i] = (i < nloc) ? 1 : 0;   // self-loop occupies slot 0 of each node's segment
    lcur[i] = 1;
  }
  __syncthreads();
  for (int i = t; i < ecnt; i += 256) atomicAdd(&lhist[bpk[ebeg + i] & (BSZ - 1)], 1);
  __syncthreads();
  {
    int v0 = lhist[2 * t], v1 = lhist[2 * t + 1];
    int s2 = v0 + v1;
    int x = s2;
    ssc[t] = x;
    for (int off = 1; off < 256; off <<= 1) {
      __syncthreads();
      int y = (t >= off) ? ssc[t - off] : 0;
      __syncthreads();
      x += y;
      ssc[t] = x;
    }
    int ex = x - s2;
    lscan[2 * t] = ex;
    lscan[2 * t + 1] = ex + v0;
  }
  __syncthreads();
  // CSR offsets + self-loop records
  for (int i = t; i < nloc; i += 256) {
    offs[nbeg + i] = aeg + lscan[i];
    staged[lscan[i]] = ((unsigned int)(nbeg + i) << BSH) | (unsigned int)i;
  }
  __syncthreads();
  // scatter edges (slots after the self-loop)
  for (int i = t; i < ecnt; i += 256) {
    unsigned int v = bpk[ebeg + i];
    int dl = v & (BSZ - 1);
    int idx = lscan[dl] + atomicAdd(&lcur[dl], 1);
    if (idx < CAPB) staged[idx] = v;
    else pk2[aeg + idx] = v;  // statistically never
  }
  __syncthreads();
  int lim = min(total, CAPB);
  for (int i = t; i < lim; i += 256) pk2[aeg + i] = staged[i];
}

// ============================ edge weights ============================
// one block per bucket; thread per edge record: w[h][e] = exp(leaky(asrc[s][h] + adst[d][h]))
__global__ __launch_bounds__(256) void k_edgew(const unsigned int* __restrict__ pk2,
                                               const int* __restrict__ abase,
                                               const float* __restrict__ asrc, const float* __restrict__ adst,
                                               half_t* __restrict__ wh) {
  int b = blockIdx.x;
  int t = threadIdx.x;
  int nbeg = b << BSH;
  int ebeg = abase[b];
  int eend = (b + 1 < NBK) ? abase[b + 1] : NT;
  for (int e = ebeg + t; e < eend; e += 256) {
    unsigned int pk = pk2[e];
    int s = (int)(pk >> BSH);
    int d = nbeg + (int)(pk & (BSZ - 1));
    f32x4 as = *(const f32x4*)(asrc + (size_t)s * 4);
    f32x4 ad = *(const f32x4*)(adst + (size_t)d * 4);
#pragma unroll
    for (int h = 0; h < 4; h++) {
      float ev = as[h] + ad[h];
      ev = (ev > 0.f) ? ev : 0.2f * ev;
      wh[(size_t)h * NT + e] = (half_t)__expf(ev);
    }
  }
}

// per-node inverse denominators: inv[h][n] = 1 / sum_e w[h][e]
__global__ __launch_bounds__(256) void k_wsum(const half_t* __restrict__ wh, const int* __restrict__ offs,
                                              float* __restrict__ inv) {
  int n = blockIdx.x * 256 + threadIdx.x;
  if (n >= NN) return;
  int beg = offs[n], end = offs[n + 1];
#pragma unroll
  for (int h = 0; h < 4; h++) {
    float s = 0.f;
    for (int e = beg; e < end; e++) s += (float)wh[(size_t)h * NT + e];
    inv[(size_t)h * NN + n] = 1.0f / (s + 1e-16f);
  }
}

// ============================ slice-based aggregation ============================
// H slice-major: H[slice][node][16]. slice = blockIdx.x & 7 -> XCD-affine (round-robin heuristic):
// each XCD's L2 only sees one 3.2 MB slice. Thread per node, 16 fp32 accumulators.
__global__ __launch_bounds__(256) void k_slice(const half_t* __restrict__ H, const unsigned int* __restrict__ pk2,
                                               const half_t* __restrict__ wh, const float* __restrict__ inv,
                                               const int* __restrict__ offs, const float* __restrict__ bias,
                                               half_t* __restrict__ out) {
  int slice = blockIdx.x & 7;
  int head = slice >> 1;
  int n = (blockIdx.x >> 3) * 256 + threadIdx.x;
  if (n >= NN) return;
  const half_t* __restrict__ Hs = H + (size_t)slice * NN * 16;
  const half_t* __restrict__ whh = wh + (size_t)head * NT;
  int beg = offs[n], end = offs[n + 1];
  float scale = inv[(size_t)head * NN + n];
  float acc[16];
#pragma unroll
  for (int j = 0; j < 16; j++) acc[j] = 0.f;
  int e = beg;
  unsigned int pk = (e < end) ? pk2[e] : 0u;
  float w = (e < end) ? (float)whh[e] : 0.f;
  while (e < end) {
    int en = e + 1;
    unsigned int pkn = 0u;
    float wn = 0.f;
    if (en < end) { pkn = pk2[en]; wn = (float)whh[en]; }  // prefetch next
    int s = (int)(pk >> BSH);
    const f16x8* hp = (const f16x8*)(Hs + (size_t)s * 16);
    f16x8 h0 = hp[0], h1 = hp[1];
#pragma unroll
    for (int j = 0; j < 8; j++) acc[j] += w * (float)h0[j];
#pragma unroll
    for (int j = 0; j < 8; j++) acc[8 + j] += w * (float)h1[j];
    pk = pkn; w = wn; e = en;
  }
  f16x8 o0, o1;
#pragma unroll
  for (int j = 0; j < 8; j++) {
    o0[j] = (half_t)fmaxf(acc[j] * scale + bias[slice * 16 + j], 0.f);
    o1[j] = (half_t)fmaxf(acc[8 + j] * scale + bias[slice * 16 + 8 + j], 0.f);
  }
  f16x8* op = (f16x8*)(out + (size_t)slice * NN * 16 + (size_t)n * 16);
  op[0] = o0;
  op[1] = o1;
}

// ============================ MFMA GEMM + attention logits ============================
// H(fp16, slice-major) = fp16(X) @ fp16(W); asrc/adst fp32 logits from C-fragments.
// X is fp32 node-major (layer 1) or fp16 slice-major (layer 2).
template <typename T>
__global__ __launch_bounds__(256) void k_gemm_att(const T* __restrict__ X, const float* __restrict__ W,
                                                  const float* __restrict__ atts, const float* __restrict__ attd,
                                                  half_t* __restrict__ H, float* __restrict__ asrc,
                                                  float* __restrict__ adst) {
  __shared__ __align__(16) half_t Xt[128 * 40];   // [row][k], stride 40 halves
  __shared__ __align__(16) half_t Wt[128 * 40];   // [n][k], stride 40 halves
  int t = threadIdx.x;
  int wave = t >> 6, lane = t & 63;
  int l15 = lane & 15, quad = lane >> 4;
  int rb = blockIdx.x * 128;

  f32x4 acc[2][8];
#pragma unroll
  for (int rt = 0; rt < 2; rt++)
#pragma unroll
    for (int ct = 0; ct < 8; ct++) acc[rt][ct] = (f32x4){0.f, 0.f, 0.f, 0.f};

  for (int k0 = 0; k0 < 128; k0 += 32) {
    __syncthreads();
    if constexpr (sizeof(T) == 4) {
      // fp32 node-major input
#pragma unroll
      for (int i = 0; i < 4; i++) {
        int lin = i * 256 + t;
        int row = lin >> 3;
        int c4 = (lin & 7) * 4;
        float4 v = make_float4(0.f, 0.f, 0.f, 0.f);
        int gr = rb + row;
        if (gr < NN) v = *(const float4*)((const float*)X + (size_t)gr * 128 + k0 + c4);
        f16x4 hv;
        hv[0] = (half_t)v.x; hv[1] = (half_t)v.y; hv[2] = (half_t)v.z; hv[3] = (half_t)v.w;
        *(f16x4*)(Xt + row * 40 + c4) = hv;
      }
    } else {
      // fp16 slice-major input: ch = k0+c8 -> slice = ch>>4, off = ch&15
#pragma unroll
      for (int i = 0; i < 2; i++) {
        int lin = i * 256 + t;
        int row = lin >> 2;
        int c8 = (lin & 3) * 8;
        int ch = k0 + c8;
        f16x8 hv = (f16x8)(half_t)0;
        int gr = rb + row;
        if (gr < NN)
          hv = *(const f16x8*)((const half_t*)X + (size_t)(ch >> 4) * NN * 16 + (size_t)gr * 16 + (ch & 15));
        *(f16x8*)(Xt + row * 40 + c8) = hv;
      }
    }
#pragma unroll
    for (int i = 0; i < 4; i++) {
      int lin = i * 256 + t;
      int kr = lin >> 5;
      int n4 = (lin & 31) * 4;
      float4 v = *(const float4*)(W + (size_t)(k0 + kr) * 128 + n4);
      Wt[(n4 + 0) * 40 + kr] = (half_t)v.x;
      Wt[(n4 + 1) * 40 + kr] = (half_t)v.y;
      Wt[(n4 + 2) * 40 + kr] = (half_t)v.z;
      Wt[(n4 + 3) * 40 + kr] = (half_t)v.w;
    }
    __syncthreads();

    f16x8 a0 = *(const f16x8*)(Xt + (wave * 32 + l15) * 40 + quad * 8);
    f16x8 a1 = *(const f16x8*)(Xt + (wave * 32 + 16 + l15) * 40 + quad * 8);
#pragma unroll
    for (int ct = 0; ct < 8; ct++) {
      f16x8 b = *(const f16x8*)(Wt + (ct * 16 + l15) * 40 + quad * 8);
      acc[0][ct] = __builtin_amdgcn_mfma_f32_16x16x32_f16(a0, b, acc[0][ct], 0, 0, 0);
      acc[1][ct] = __builtin_amdgcn_mfma_f32_16x16x32_f16(a1, b, acc[1][ct], 0, 0, 0);
    }
  }

  // ---- store H slice-major: slice = ct, within = l15 ----
#pragma unroll
  for (int rt = 0; rt < 2; rt++) {
    int rbase = rb + wave * 32 + rt * 16 + quad * 4;
#pragma unroll
    for (int reg = 0; reg < 4; reg++) {
      int row = rbase + reg;
      if (row < NN) {
#pragma unroll
        for (int ct = 0; ct < 8; ct++) {
          H[(size_t)ct * NN * 16 + (size_t)row * 16 + l15] = (half_t)acc[rt][ct][reg];
        }
      }
    }
  }

  // ---- attention logits ----
  float s_lo[4], s_hi[4], d_lo[4], d_hi[4];
#pragma unroll
  for (int h = 0; h < 4; h++) {
    s_lo[h] = atts[h * 32 + l15];
    s_hi[h] = atts[h * 32 + 16 + l15];
    d_lo[h] = attd[h * 32 + l15];
    d_hi[h] = attd[h * 32 + 16 + l15];
  }
#pragma unroll
  for (int rt = 0; rt < 2; rt++) {
    float ps[4][4], pd[4][4];  // [reg][head]
#pragma unroll
    for (int reg = 0; reg < 4; reg++)
#pragma unroll
      for (int h = 0; h < 4; h++) {
        ps[reg][h] = acc[rt][2 * h][reg] * s_lo[h] + acc[rt][2 * h + 1][reg] * s_hi[h];
        pd[reg][h] = acc[rt][2 * h][reg] * d_lo[h] + acc[rt][2 * h + 1][reg] * d_hi[h];
      }
#pragma unroll
    for (int m = 1; m < 16; m <<= 1) {
#pragma unroll
      for (int reg = 0; reg < 4; reg++)
#pragma unroll
        for (int h = 0; h < 4; h++) {
          ps[reg][h] += __shfl_xor(ps[reg][h], m, 64);
          pd[reg][h] += __shfl_xor(pd[reg][h], m, 64);
        }
    }
    float vs = 0.f, vd = 0.f;
#pragma unroll
    for (int reg = 0; reg < 4; reg++)
#pragma unroll
      for (int h = 0; h < 4; h++) {
        if (l15 == reg * 4 + h) { vs = ps[reg][h]; vd = pd[reg][h]; }
      }
    int row = rb + wave * 32 + rt * 16 + quad * 4 + (l15 >> 2);
    int h = l15 & 3;
    if (row < NN) {
      asrc[row * 4 + h] = vs;
      adst[row * 4 + h] = vd;
    }
  }
}

// ============================ classifier (MFMA, N=40 padded to 48) ============================
__global__ __launch_bounds__(256) void k_classifier(const half_t* __restrict__ Hf, const float* __restrict__ Wc,
                                                    const float* __restrict__ bc, float* __restrict__ out) {
  __shared__ __align__(16) half_t Xt[128 * 40];
  __shared__ __align__(16) half_t Wt[48 * 40];
  int t = threadIdx.x;
  int wave = t >> 6, lane = t & 63;
  int l15 = lane & 15, quad = lane >> 4;
  int rb = blockIdx.x * 128;

  f32x4 acc[2][3];
#pragma unroll
  for (int rt = 0; rt < 2; rt++)
#pragma unroll
    for (int ct = 0; ct < 3; ct++) acc[rt][ct] = (f32x4){0.f, 0.f, 0.f, 0.f};

  for (int k0 = 0; k0 < 128; k0 += 32) {
    __syncthreads();
#pragma unroll
    for (int i = 0; i < 2; i++) {
      int lin = i * 256 + t;
      int row = lin >> 2;
      int c8 = (lin & 3) * 8;
      int ch = k0 + c8;
      f16x8 hv = (f16x8)(half_t)0;
      int gr = rb + row;
      if (gr < NN)
        hv = *(const f16x8*)(Hf + (size_t)(ch >> 4) * NN * 16 + (size_t)gr * 16 + (ch & 15));
      *(f16x8*)(Xt + row * 40 + c8) = hv;
    }
#pragma unroll
    for (int i = 0; i < 6; i++) {
      int lin = i * 256 + t;
      int kr = lin / 48;
      int n = lin - kr * 48;
      Wt[n * 40 + kr] = (n < 40) ? (half_t)Wc[(size_t)(k0 + kr) * 40 + n] : (half_t)0;
    }
    __syncthreads();

    f16x8 a0 = *(const f16x8*)(Xt + (wave * 32 + l15) * 40 + quad * 8);
    f16x8 a1 = *(const f16x8*)(Xt + (wave * 32 + 16 + l15) * 40 + quad * 8);
#pragma unroll
    for (int ct = 0; ct < 3; ct++) {
      f16x8 b = *(const f16x8*)(Wt + (ct * 16 + l15) * 40 + quad * 8);
      acc[0][ct] = __builtin_amdgcn_mfma_f32_16x16x32_f16(a0, b, acc[0][ct], 0, 0, 0);
      acc[1][ct] = __builtin_amdgcn_mfma_f32_16x16x32_f16(a1, b, acc[1][ct], 0, 0, 0);
    }
  }

#pragma unroll
  for (int rt = 0; rt < 2; rt++) {
#pragma unroll
    for (int ct = 0; ct < 3; ct++) {
      int col = ct * 16 + l15;
      if (col < 40) {
        float bv = bc[col];
#pragma unroll
        for (int reg = 0; reg < 4; reg++) {
          int row = rb + wave * 32 + rt * 16 + quad * 4 + reg;
          if (row < NN) out[(size_t)row * 40 + col] = acc[rt][ct][reg] + bv;
        }
      }
    }
  }
}

// ============================ launch ============================

extern "C" void kernel_launch(void* const* d_in, const int* in_sizes, int n_in,
                              void* d_out, int out_size, void* d_ws, size_t ws_size,
                              hipStream_t stream) {
  const float* x   = (const float*)d_in[0];
  const int*   ei  = (const int*)d_in[1];
  const float* W1  = (const float*)d_in[2];
  const float* as1 = (const float*)d_in[3];
  const float* ad1 = (const float*)d_in[4];
  const float* b1  = (const float*)d_in[5];
  const float* W2  = (const float*)d_in[6];
  const float* as2 = (const float*)d_in[7];
  const float* ad2 = (const float*)d_in[8];
  const float* b2  = (const float*)d_in[9];
  const float* Wc  = (const float*)d_in[10];
  const float* bc  = (const float*)d_in[11];
  float* out = (float*)d_out;

  const int* esrc = ei;
  const int* edst = ei + NE;

  char* w = (char*)d_ws;
  auto alloc = [&](size_t bytes) {
    void* p = (void*)w;
    w += (bytes + 255) & ~(size_t)255;
    return p;
  };
  half_t* A   = (half_t*)alloc(sizeof(half_t) * (size_t)NN * 128);  // slice-major gather target
  half_t* B   = (half_t*)alloc(sizeof(half_t) * (size_t)NN * 128);  // slice-major layer output
  float* asrc = (float*)alloc(sizeof(float) * (size_t)NN * 4);
  float* adst = (float*)alloc(sizeof(float) * (size_t)NN * 4);
  float* inv  = (float*)alloc(sizeof(float) * (size_t)NN * 4);
  int* offs   = (int*)alloc(sizeof(int) * (NN + 1));
  unsigned int* bpk = (unsigned int*)alloc(sizeof(unsigned int) * NE);
  unsigned int* pk2 = (unsigned int*)alloc(sizeof(unsigned int) * NT);
  half_t* wh  = (half_t*)alloc(sizeof(half_t) * (size_t)NT * 4);
  int* bcnt   = (int*)alloc(sizeof(int) * NBK);
  int* ebase  = (int*)alloc(sizeof(int) * NBK);
  int* abase  = (int*)alloc(sizeof(int) * NBK);
  int* bcur   = (int*)alloc(sizeof(int) * NBK);

  // ---- CSR build (self-loops folded in) ----
  k_zero<<<1, 256, 0, stream>>>(bcnt, NBK);
  k_bhist<<<NBH, 256, 0, stream>>>(edst, bcnt);
  k_bscan<<<1, 256, 0, stream>>>(bcnt, ebase, abase, bcur, offs);
  k_binA<<<NBA, 256, 0, stream>>>(esrc, edst, bcur, bpk);
  k_binB<<<NBK, 256, 0, stream>>>(bpk, bcnt, ebase, abase, offs, pk2);

  // ---- layer 1 ----
  k_gemm_att<float><<<(NN + 127) / 128, 256, 0, stream>>>(x, W1, as1, ad1, A, asrc, adst);
  k_edgew<<<NBK, 256, 0, stream>>>(pk2, abase, asrc, adst, wh);
  k_wsum<<<NBN, 256, 0, stream>>>(wh, offs, inv);
  k_slice<<<NBN * 8, 256, 0, stream>>>(A, pk2, wh, inv, offs, b1, B);

  // ---- layer 2 ----
  k_gemm_att<half_t><<<(NN + 127) / 128, 256, 0, stream>>>(B, W2, as2, ad2, A, asrc, adst);
  k_edgew<<<NBK, 256, 0, stream>>>(pk2, abase, asrc, adst, wh);
  k_wsum<<<NBN, 256, 0, stream>>>(wh, offs, inv);
  k_slice<<<NBN * 8, 256, 0, stream>>>(A, pk2, wh, inv, offs, b2, B);

  // ---- classifier ----
  k_classifier<<<(NN + 127) / 128, 256, 0, stream>>>(B, Wc, bc, out);
}

// Round 5
// 564.345 us; speedup vs baseline: 1.6179x; 1.6179x over previous
//
#include <hip/hip_runtime.h>

#define NN   100000
#define NE   1600000
#define NT   1700000      // NE + NN self-loops
#define BSH  9            // 512 nodes per bucket
#define BSZ  512
#define NBK  196          // ceil(NN/512)
#define TILE_A 8192
#define NBA  196          // ceil(NE/TILE_A)
#define TILE_H 4096
#define NBH  391          // ceil(NE/TILE_H)
#define CAPB 10240        // LDS staging capacity (entries) in k_binB

typedef _Float16 half_t;
typedef __attribute__((ext_vector_type(2))) _Float16 f16x2;
typedef __attribute__((ext_vector_type(4))) _Float16 f16x4;
typedef __attribute__((ext_vector_type(8))) _Float16 f16x8;
typedef __attribute__((ext_vector_type(4))) float    f32x4;

// ============================ small utils ============================

__global__ __launch_bounds__(256) void k_zero(int* __restrict__ p, int n) {
  int i = blockIdx.x * 256 + threadIdx.x;
  if (i < n) p[i] = 0;
}

// ============================ bucket histogram ============================
__global__ __launch_bounds__(256) void k_bhist(const int* __restrict__ dst, int* __restrict__ bcnt) {
  __shared__ int h[NBK];
  int t = threadIdx.x;
  for (int i = t; i < NBK; i += 256) h[i] = 0;
  __syncthreads();
  int e0 = blockIdx.x * TILE_H;
#pragma unroll
  for (int i = 0; i < TILE_H / 256; i++) {
    int e = e0 + t + i * 256;
    if (e < NE) atomicAdd(&h[dst[e] >> BSH], 1);
  }
  __syncthreads();
  for (int i = t; i < NBK; i += 256) {
    int c = h[i];
    if (c > 0) atomicAdd(&bcnt[i], c);
  }
}

// scan bucket counts -> ebase (edges only, for bpk) and abase (edges+selfloops, for pk2/offs)
__global__ __launch_bounds__(256) void k_bscan(const int* __restrict__ bcnt, int* __restrict__ ebase,
                                               int* __restrict__ abase, int* __restrict__ bcur,
                                               int* __restrict__ offs) {
  __shared__ int sh[256];
  int t = threadIdx.x;
  int nloc = 0;
  if (t < NBK) {
    int nbeg = t << BSH;
    nloc = min(BSZ, NN - nbeg);
  }
  int ve = (t < NBK) ? bcnt[t] : 0;
  {
    int x = ve;
    sh[t] = x;
    for (int off = 1; off < 256; off <<= 1) {
      __syncthreads();
      int y = (t >= off) ? sh[t - off] : 0;
      __syncthreads();
      x += y;
      sh[t] = x;
    }
    if (t < NBK) { ebase[t] = x - ve; bcur[t] = x - ve; }
  }
  __syncthreads();
  {
    int va = ve + nloc;
    int x = va;
    sh[t] = x;
    for (int off = 1; off < 256; off <<= 1) {
      __syncthreads();
      int y = (t >= off) ? sh[t - off] : 0;
      __syncthreads();
      x += y;
      sh[t] = x;
    }
    if (t < NBK) abase[t] = x - va;
  }
  if (t == 0) offs[NN] = NT;
}

// ============================ pass A: bin edges by bucket ============================
__global__ __launch_bounds__(256) void k_binA(const int* __restrict__ src, const int* __restrict__ dst,
                                              int* __restrict__ bcur, unsigned int* __restrict__ bpk) {
  __shared__ int hist[NBK];
  __shared__ int hscan[NBK];
  __shared__ int gbase[NBK];
  __shared__ int cnt[NBK];
  __shared__ int ssc[256];
  __shared__ unsigned int staged[TILE_A];
  int t = threadIdx.x;
  int e0 = blockIdx.x * TILE_A;
  for (int i = t; i < NBK; i += 256) { hist[i] = 0; cnt[i] = 0; }
  __syncthreads();
#pragma unroll
  for (int i = 0; i < TILE_A / 256; i++) {
    int e = e0 + t + i * 256;
    if (e < NE) atomicAdd(&hist[dst[e] >> BSH], 1);
  }
  __syncthreads();
  {
    int v = (t < NBK) ? hist[t] : 0;
    int x = v;
    ssc[t] = x;
    for (int off = 1; off < 256; off <<= 1) {
      __syncthreads();
      int y = (t >= off) ? ssc[t - off] : 0;
      __syncthreads();
      x += y;
      ssc[t] = x;
    }
    if (t < NBK) {
      hscan[t] = x - v;
      if (v > 0) gbase[t] = atomicAdd(&bcur[t], v);
    }
  }
  __syncthreads();
#pragma unroll
  for (int i = 0; i < TILE_A / 256; i++) {
    int e = e0 + t + i * 256;
    if (e < NE) {
      int d = dst[e];
      int b = d >> BSH;
      int pos = hscan[b] + atomicAdd(&cnt[b], 1);
      staged[pos] = ((unsigned int)src[e] << BSH) | (unsigned int)(d & (BSZ - 1));
    }
  }
  __syncthreads();
  int wave = t >> 6, lane = t & 63;
  for (int b = wave; b < NBK; b += 4) {
    int c = hist[b];
    if (c > 0) {
      int lo = hscan[b], gb = gbase[b];
      for (int j = lane; j < c; j += 64) bpk[gb + j] = staged[lo + j];
    }
  }
}

// ============================ pass B: sort bucket by dst, add self-loops, emit offs + pk2 ============
__global__ __launch_bounds__(256) void k_binB(const unsigned int* __restrict__ bpk,
                                              const int* __restrict__ bcnt,
                                              const int* __restrict__ ebase,
                                              const int* __restrict__ abase,
                                              int* __restrict__ offs, unsigned int* __restrict__ pk2) {
  __shared__ int lhist[BSZ];
  __shared__ int lscan[BSZ];
  __shared__ int lcur[BSZ];
  __shared__ int ssc[256];
  __shared__ unsigned int staged[CAPB];
  int b = blockIdx.x;
  int t = threadIdx.x;
  int nbeg = b << BSH;
  int nloc = min(BSZ, NN - nbeg);
  int ebeg = ebase[b];
  int ecnt = bcnt[b];
  int aeg = abase[b];
  int total = ecnt + nloc;
  for (int i = t; i < BSZ; i += 256) {
    lhist[i] = (i < nloc) ? 1 : 0;   // self-loop occupies slot 0 of each node's segment
    lcur[i] = 1;
  }
  __syncthreads();
  for (int i = t; i < ecnt; i += 256) atomicAdd(&lhist[bpk[ebeg + i] & (BSZ - 1)], 1);
  __syncthreads();
  {
    int v0 = lhist[2 * t], v1 = lhist[2 * t + 1];
    int s2 = v0 + v1;
    int x = s2;
    ssc[t] = x;
    for (int off = 1; off < 256; off <<= 1) {
      __syncthreads();
      int y = (t >= off) ? ssc[t - off] : 0;
      __syncthreads();
      x += y;
      ssc[t] = x;
    }
    int ex = x - s2;
    lscan[2 * t] = ex;
    lscan[2 * t + 1] = ex + v0;
  }
  __syncthreads();
  for (int i = t; i < nloc; i += 256) {
    offs[nbeg + i] = aeg + lscan[i];
    staged[lscan[i]] = ((unsigned int)(nbeg + i) << BSH) | (unsigned int)i;
  }
  __syncthreads();
  for (int i = t; i < ecnt; i += 256) {
    unsigned int v = bpk[ebeg + i];
    int dl = v & (BSZ - 1);
    int idx = lscan[dl] + atomicAdd(&lcur[dl], 1);
    if (idx < CAPB) staged[idx] = v;
    else pk2[aeg + idx] = v;  // statistically never
  }
  __syncthreads();
  int lim = min(total, CAPB);
  for (int i = t; i < lim; i += 256) pk2[aeg + i] = staged[i];
}

// ============================ fused edge weights + inverse denominators ============================
// one block per bucket: wh[h][e] = exp(leaky(asrc[s][h]+adst[d][h])); inv[h][n] = 1/sum_e wh
__global__ __launch_bounds__(256) void k_edgew(const unsigned int* __restrict__ pk2,
                                               const int* __restrict__ abase,
                                               const float* __restrict__ asrc, const float* __restrict__ adst,
                                               half_t* __restrict__ wh, float* __restrict__ inv) {
  __shared__ float lsum[4][BSZ];
  int b = blockIdx.x;
  int t = threadIdx.x;
  int nbeg = b << BSH;
  int nloc = min(BSZ, NN - nbeg);
  int ebeg = abase[b];
  int eend = (b + 1 < NBK) ? abase[b + 1] : NT;
  for (int i = t; i < BSZ; i += 256) {
    lsum[0][i] = 0.f; lsum[1][i] = 0.f; lsum[2][i] = 0.f; lsum[3][i] = 0.f;
  }
  __syncthreads();
  for (int e = ebeg + t; e < eend; e += 256) {
    unsigned int pk = pk2[e];
    int s = (int)(pk >> BSH);
    int dl = (int)(pk & (BSZ - 1));
    f32x4 as = *(const f32x4*)(asrc + (size_t)s * 4);
    f32x4 ad = *(const f32x4*)(adst + (size_t)(nbeg + dl) * 4);
#pragma unroll
    for (int h = 0; h < 4; h++) {
      float ev = as[h] + ad[h];
      ev = (ev > 0.f) ? ev : 0.2f * ev;
      float w = __expf(ev);
      wh[(size_t)h * NT + e] = (half_t)w;
      atomicAdd(&lsum[h][dl], w);
    }
  }
  __syncthreads();
  for (int i = t; i < nloc; i += 256) {
#pragma unroll
    for (int h = 0; h < 4; h++) inv[(size_t)h * NN + nbeg + i] = 1.0f / (lsum[h][i] + 1e-16f);
  }
}

// ============================ per-node gather aggregation ============================
// one wave per dst node; 16 lanes x half8 per row; 4 edges in flight; pure weighted gather.
__global__ __launch_bounds__(256) void k_aggregate(const half_t* __restrict__ H, const int* __restrict__ offs,
                                                   const unsigned int* __restrict__ pk2,
                                                   const half_t* __restrict__ wh, const float* __restrict__ inv,
                                                   const float* __restrict__ bias, half_t* __restrict__ out) {
  int n = blockIdx.x * 4 + (threadIdx.x >> 6);
  if (n >= NN) return;
  int lane = threadIdx.x & 63;
  int l15 = lane & 15, g = lane >> 4;
  int head = l15 >> 2;
  const half_t* __restrict__ whh = wh + (size_t)head * NT;
  float acc[8] = {0.f, 0.f, 0.f, 0.f, 0.f, 0.f, 0.f, 0.f};
  int beg = offs[n], end = offs[n + 1];
  int i = beg + g;
  int s = 0;
  float w = 0.f;
  if (i < end) {
    s = (int)(pk2[i] >> BSH);
    w = (float)whh[i];
  }
  while (i < end) {
    int inext = i + 4;
    int snext = 0;
    float wn = 0.f;
    if (inext < end) {              // prefetch: independent of this iter's use
      snext = (int)(pk2[inext] >> BSH);
      wn = (float)whh[inext];
    }
    f16x8 hv = *(const f16x8*)(H + (size_t)s * 128 + l15 * 8);
#pragma unroll
    for (int j = 0; j < 8; j++) acc[j] += w * (float)hv[j];
    s = snext; w = wn; i = inext;
  }
#pragma unroll
  for (int m = 16; m < 64; m <<= 1) {
#pragma unroll
    for (int j = 0; j < 8; j++) acc[j] += __shfl_xor(acc[j], m, 64);
  }
  float scale = inv[(size_t)head * NN + n];
  float o0 = acc[0], o1 = acc[1];
  if (g == 1) { o0 = acc[2]; o1 = acc[3]; }
  if (g == 2) { o0 = acc[4]; o1 = acc[5]; }
  if (g == 3) { o0 = acc[6]; o1 = acc[7]; }
  int ch = l15 * 8 + g * 2;
  o0 = fmaxf(o0 * scale + bias[ch], 0.f);
  o1 = fmaxf(o1 * scale + bias[ch + 1], 0.f);
  f16x2 o;
  o[0] = (half_t)o0;
  o[1] = (half_t)o1;
  *(f16x2*)(out + (size_t)n * 128 + ch) = o;
}

// ============================ MFMA GEMM + attention logits ============================
// H(fp16 node-major) = fp16(X) @ fp16(W); asrc/adst fp32 logits from C-fragments.
template <typename T>
__global__ __launch_bounds__(256) void k_gemm_att(const T* __restrict__ X, const float* __restrict__ W,
                                                  const float* __restrict__ atts, const float* __restrict__ attd,
                                                  half_t* __restrict__ H, float* __restrict__ asrc,
                                                  float* __restrict__ adst) {
  __shared__ __align__(16) half_t Xt[128 * 40];   // [row][k], stride 40 halves
  __shared__ __align__(16) half_t Wt[128 * 40];   // [n][k], stride 40 halves
  int t = threadIdx.x;
  int wave = t >> 6, lane = t & 63;
  int l15 = lane & 15, quad = lane >> 4;
  int rb = blockIdx.x * 128;

  f32x4 acc[2][8];
#pragma unroll
  for (int rt = 0; rt < 2; rt++)
#pragma unroll
    for (int ct = 0; ct < 8; ct++) acc[rt][ct] = (f32x4){0.f, 0.f, 0.f, 0.f};

  for (int k0 = 0; k0 < 128; k0 += 32) {
    __syncthreads();
    if constexpr (sizeof(T) == 4) {
#pragma unroll
      for (int i = 0; i < 4; i++) {
        int lin = i * 256 + t;
        int row = lin >> 3;
        int c4 = (lin & 7) * 4;
        float4 v = make_float4(0.f, 0.f, 0.f, 0.f);
        int gr = rb + row;
        if (gr < NN) v = *(const float4*)((const float*)X + (size_t)gr * 128 + k0 + c4);
        f16x4 hv;
        hv[0] = (half_t)v.x; hv[1] = (half_t)v.y; hv[2] = (half_t)v.z; hv[3] = (half_t)v.w;
        *(f16x4*)(Xt + row * 40 + c4) = hv;
      }
    } else {
#pragma unroll
      for (int i = 0; i < 2; i++) {
        int lin = i * 256 + t;
        int row = lin >> 2;
        int c8 = (lin & 3) * 8;
        f16x8 hv = (f16x8)(half_t)0;
        int gr = rb + row;
        if (gr < NN) hv = *(const f16x8*)((const half_t*)X + (size_t)gr * 128 + k0 + c8);
        *(f16x8*)(Xt + row * 40 + c8) = hv;
      }
    }
#pragma unroll
    for (int i = 0; i < 4; i++) {
      int lin = i * 256 + t;
      int kr = lin >> 5;
      int n4 = (lin & 31) * 4;
      float4 v = *(const float4*)(W + (size_t)(k0 + kr) * 128 + n4);
      Wt[(n4 + 0) * 40 + kr] = (half_t)v.x;
      Wt[(n4 + 1) * 40 + kr] = (half_t)v.y;
      Wt[(n4 + 2) * 40 + kr] = (half_t)v.z;
      Wt[(n4 + 3) * 40 + kr] = (half_t)v.w;
    }
    __syncthreads();

    f16x8 a0 = *(const f16x8*)(Xt + (wave * 32 + l15) * 40 + quad * 8);
    f16x8 a1 = *(const f16x8*)(Xt + (wave * 32 + 16 + l15) * 40 + quad * 8);
#pragma unroll
    for (int ct = 0; ct < 8; ct++) {
      f16x8 b = *(const f16x8*)(Wt + (ct * 16 + l15) * 40 + quad * 8);
      acc[0][ct] = __builtin_amdgcn_mfma_f32_16x16x32_f16(a0, b, acc[0][ct], 0, 0, 0);
      acc[1][ct] = __builtin_amdgcn_mfma_f32_16x16x32_f16(a1, b, acc[1][ct], 0, 0, 0);
    }
  }

  // ---- store H node-major fp16 ----
#pragma unroll
  for (int rt = 0; rt < 2; rt++) {
    int rbase = rb + wave * 32 + rt * 16 + quad * 4;
#pragma unroll
    for (int reg = 0; reg < 4; reg++) {
      int row = rbase + reg;
      if (row < NN) {
#pragma unroll
        for (int ct = 0; ct < 8; ct++) {
          H[(size_t)row * 128 + ct * 16 + l15] = (half_t)acc[rt][ct][reg];
        }
      }
    }
  }

  // ---- attention logits ----
  float s_lo[4], s_hi[4], d_lo[4], d_hi[4];
#pragma unroll
  for (int h = 0; h < 4; h++) {
    s_lo[h] = atts[h * 32 + l15];
    s_hi[h] = atts[h * 32 + 16 + l15];
    d_lo[h] = attd[h * 32 + l15];
    d_hi[h] = attd[h * 32 + 16 + l15];
  }
#pragma unroll
  for (int rt = 0; rt < 2; rt++) {
    float ps[4][4], pd[4][4];  // [reg][head]
#pragma unroll
    for (int reg = 0; reg < 4; reg++)
#pragma unroll
      for (int h = 0; h < 4; h++) {
        ps[reg][h] = acc[rt][2 * h][reg] * s_lo[h] + acc[rt][2 * h + 1][reg] * s_hi[h];
        pd[reg][h] = acc[rt][2 * h][reg] * d_lo[h] + acc[rt][2 * h + 1][reg] * d_hi[h];
      }
#pragma unroll
    for (int m = 1; m < 16; m <<= 1) {
#pragma unroll
      for (int reg = 0; reg < 4; reg++)
#pragma unroll
        for (int h = 0; h < 4; h++) {
          ps[reg][h] += __shfl_xor(ps[reg][h], m, 64);
          pd[reg][h] += __shfl_xor(pd[reg][h], m, 64);
        }
    }
    float vs = 0.f, vd = 0.f;
#pragma unroll
    for (int reg = 0; reg < 4; reg++)
#pragma unroll
      for (int h = 0; h < 4; h++) {
        if (l15 == reg * 4 + h) { vs = ps[reg][h]; vd = pd[reg][h]; }
      }
    int row = rb + wave * 32 + rt * 16 + quad * 4 + (l15 >> 2);
    int h = l15 & 3;
    if (row < NN) {
      asrc[row * 4 + h] = vs;
      adst[row * 4 + h] = vd;
    }
  }
}

// ============================ classifier (MFMA, N=40 padded to 48) ============================
__global__ __launch_bounds__(256) void k_classifier(const half_t* __restrict__ Hf, const float* __restrict__ Wc,
                                                    const float* __restrict__ bc, float* __restrict__ out) {
  __shared__ __align__(16) half_t Xt[128 * 40];
  __shared__ __align__(16) half_t Wt[48 * 40];
  int t = threadIdx.x;
  int wave = t >> 6, lane = t & 63;
  int l15 = lane & 15, quad = lane >> 4;
  int rb = blockIdx.x * 128;

  f32x4 acc[2][3];
#pragma unroll
  for (int rt = 0; rt < 2; rt++)
#pragma unroll
    for (int ct = 0; ct < 3; ct++) acc[rt][ct] = (f32x4){0.f, 0.f, 0.f, 0.f};

  for (int k0 = 0; k0 < 128; k0 += 32) {
    __syncthreads();
#pragma unroll
    for (int i = 0; i < 2; i++) {
      int lin = i * 256 + t;
      int row = lin >> 2;
      int c8 = (lin & 3) * 8;
      f16x8 hv = (f16x8)(half_t)0;
      int gr = rb + row;
      if (gr < NN) hv = *(const f16x8*)(Hf + (size_t)gr * 128 + k0 + c8);
      *(f16x8*)(Xt + row * 40 + c8) = hv;
    }
#pragma unroll
    for (int i = 0; i < 6; i++) {
      int lin = i * 256 + t;
      int kr = lin / 48;
      int n = lin - kr * 48;
      Wt[n * 40 + kr] = (n < 40) ? (half_t)Wc[(size_t)(k0 + kr) * 40 + n] : (half_t)0;
    }
    __syncthreads();

    f16x8 a0 = *(const f16x8*)(Xt + (wave * 32 + l15) * 40 + quad * 8);
    f16x8 a1 = *(const f16x8*)(Xt + (wave * 32 + 16 + l15) * 40 + quad * 8);
#pragma unroll
    for (int ct = 0; ct < 3; ct++) {
      f16x8 b = *(const f16x8*)(Wt + (ct * 16 + l15) * 40 + quad * 8);
      acc[0][ct] = __builtin_amdgcn_mfma_f32_16x16x32_f16(a0, b, acc[0][ct], 0, 0, 0);
      acc[1][ct] = __builtin_amdgcn_mfma_f32_16x16x32_f16(a1, b, acc[1][ct], 0, 0, 0);
    }
  }

#pragma unroll
  for (int rt = 0; rt < 2; rt++) {
#pragma unroll
    for (int ct = 0; ct < 3; ct++) {
      int col = ct * 16 + l15;
      if (col < 40) {
        float bv = bc[col];
#pragma unroll
        for (int reg = 0; reg < 4; reg++) {
          int row = rb + wave * 32 + rt * 16 + quad * 4 + reg;
          if (row < NN) out[(size_t)row * 40 + col] = acc[rt][ct][reg] + bv;
        }
      }
    }
  }
}

// ============================ launch ============================

extern "C" void kernel_launch(void* const* d_in, const int* in_sizes, int n_in,
                              void* d_out, int out_size, void* d_ws, size_t ws_size,
                              hipStream_t stream) {
  const float* x   = (const float*)d_in[0];
  const int*   ei  = (const int*)d_in[1];
  const float* W1  = (const float*)d_in[2];
  const float* as1 = (const float*)d_in[3];
  const float* ad1 = (const float*)d_in[4];
  const float* b1  = (const float*)d_in[5];
  const float* W2  = (const float*)d_in[6];
  const float* as2 = (const float*)d_in[7];
  const float* ad2 = (const float*)d_in[8];
  const float* b2  = (const float*)d_in[9];
  const float* Wc  = (const float*)d_in[10];
  const float* bc  = (const float*)d_in[11];
  float* out = (float*)d_out;

  const int* esrc = ei;
  const int* edst = ei + NE;

  char* w = (char*)d_ws;
  auto alloc = [&](size_t bytes) {
    void* p = (void*)w;
    w += (bytes + 255) & ~(size_t)255;
    return p;
  };
  half_t* A   = (half_t*)alloc(sizeof(half_t) * (size_t)NN * 128);  // node-major gather target
  half_t* B   = (half_t*)alloc(sizeof(half_t) * (size_t)NN * 128);  // node-major layer output
  float* asrc = (float*)alloc(sizeof(float) * (size_t)NN * 4);
  float* adst = (float*)alloc(sizeof(float) * (size_t)NN * 4);
  float* inv  = (float*)alloc(sizeof(float) * (size_t)NN * 4);
  int* offs   = (int*)alloc(sizeof(int) * (NN + 1));
  unsigned int* bpk = (unsigned int*)alloc(sizeof(unsigned int) * NE);
  unsigned int* pk2 = (unsigned int*)alloc(sizeof(unsigned int) * NT);
  half_t* wh  = (half_t*)alloc(sizeof(half_t) * (size_t)NT * 4);
  int* bcnt   = (int*)alloc(sizeof(int) * NBK);
  int* ebase  = (int*)alloc(sizeof(int) * NBK);
  int* abase  = (int*)alloc(sizeof(int) * NBK);
  int* bcur   = (int*)alloc(sizeof(int) * NBK);

  // ---- CSR build (self-loops folded in) ----
  k_zero<<<1, 256, 0, stream>>>(bcnt, NBK);
  k_bhist<<<NBH, 256, 0, stream>>>(edst, bcnt);
  k_bscan<<<1, 256, 0, stream>>>(bcnt, ebase, abase, bcur, offs);
  k_binA<<<NBA, 256, 0, stream>>>(esrc, edst, bcur, bpk);
  k_binB<<<NBK, 256, 0, stream>>>(bpk, bcnt, ebase, abase, offs, pk2);

  // ---- layer 1 ----
  k_gemm_att<float><<<(NN + 127) / 128, 256, 0, stream>>>(x, W1, as1, ad1, A, asrc, adst);
  k_edgew<<<NBK, 256, 0, stream>>>(pk2, abase, asrc, adst, wh, inv);
  k_aggregate<<<(NN + 3) / 4, 256, 0, stream>>>(A, offs, pk2, wh, inv, b1, B);

  // ---- layer 2 ----
  k_gemm_att<half_t><<<(NN + 127) / 128, 256, 0, stream>>>(B, W2, as2, ad2, A, asrc, adst);
  k_edgew<<<NBK, 256, 0, stream>>>(pk2, abase, asrc, adst, wh, inv);
  k_aggregate<<<(NN + 3) / 4, 256, 0, stream>>>(A, offs, pk2, wh, inv, b2, B);

  // ---- classifier ----
  k_classifier<<<(NN + 127) / 128, 256, 0, stream>>>(B, Wc, bc, out);
}

// Round 6
// 478.510 us; speedup vs baseline: 1.9081x; 1.1794x over previous
//
#include <hip/hip_runtime.h>

#define NN   100000
#define NE   1600000
#define NT   1700000      // NE + NN self-loops
#define BSH  8            // 256 nodes per bucket
#define BSZ  256
#define NBK  391          // ceil(NN/256)
#define TA   8192         // edges per binA block
#define NBA  196          // ceil(NE/TA)
#define NBH  391          // ceil((NE/4)/1024)
#define CAPB 6400         // LDS staging capacity (entries) in k_binB

typedef _Float16 half_t;
typedef __attribute__((ext_vector_type(2))) _Float16 f16x2;
typedef __attribute__((ext_vector_type(4))) _Float16 f16x4;
typedef __attribute__((ext_vector_type(8))) _Float16 f16x8;
typedef __attribute__((ext_vector_type(4))) float    f32x4;

// ============================ small utils ============================

__global__ __launch_bounds__(256) void k_zero(int* __restrict__ p, int n) {
  int i = blockIdx.x * 256 + threadIdx.x;
  if (i < n) p[i] = 0;
}

// ============================ bucket histogram (int4 loads) ============================
__global__ __launch_bounds__(256) void k_bhist(const int* __restrict__ dst, int* __restrict__ bcnt) {
  __shared__ int h[NBK];
  int t = threadIdx.x;
  for (int i = t; i < NBK; i += 256) h[i] = 0;
  __syncthreads();
  const int4* d4 = (const int4*)dst;
  int base = blockIdx.x * 1024;
#pragma unroll
  for (int i = 0; i < 4; i++) {
    int idx = base + t + i * 256;
    if (idx < NE / 4) {
      int4 v = d4[idx];
      atomicAdd(&h[v.x >> BSH], 1);
      atomicAdd(&h[v.y >> BSH], 1);
      atomicAdd(&h[v.z >> BSH], 1);
      atomicAdd(&h[v.w >> BSH], 1);
    }
  }
  __syncthreads();
  for (int i = t; i < NBK; i += 256) {
    int c = h[i];
    if (c > 0) atomicAdd(&bcnt[i], c);
  }
}

// scan bucket counts (2 elems/thread) -> ebase (edges, for bpk), abase (edges+loops), bcur
__global__ __launch_bounds__(256) void k_bscan(const int* __restrict__ bcnt, int* __restrict__ ebase,
                                               int* __restrict__ abase, int* __restrict__ bcur,
                                               int* __restrict__ offs) {
  __shared__ int sh[256];
  int t = threadIdx.x;
  int i0 = 2 * t, i1 = 2 * t + 1;
  int ve0 = (i0 < NBK) ? bcnt[i0] : 0;
  int ve1 = (i1 < NBK) ? bcnt[i1] : 0;
  int nl0 = (i0 < NBK) ? min(BSZ, NN - (i0 << BSH)) : 0;
  int nl1 = (i1 < NBK) ? min(BSZ, NN - (i1 << BSH)) : 0;
  // scan 1: edges only
  {
    int s2 = ve0 + ve1;
    int x = s2;
    sh[t] = x;
    for (int off = 1; off < 256; off <<= 1) {
      __syncthreads();
      int y = (t >= off) ? sh[t - off] : 0;
      __syncthreads();
      x += y;
      sh[t] = x;
    }
    int ex = x - s2;
    if (i0 < NBK) { ebase[i0] = ex; bcur[i0] = ex; }
    if (i1 < NBK) { ebase[i1] = ex + ve0; bcur[i1] = ex + ve0; }
  }
  __syncthreads();
  // scan 2: edges + self-loops
  {
    int a0 = ve0 + nl0, a1 = ve1 + nl1;
    int s2 = a0 + a1;
    int x = s2;
    sh[t] = x;
    for (int off = 1; off < 256; off <<= 1) {
      __syncthreads();
      int y = (t >= off) ? sh[t - off] : 0;
      __syncthreads();
      x += y;
      sh[t] = x;
    }
    int ex = x - s2;
    if (i0 < NBK) abase[i0] = ex;
    if (i1 < NBK) abase[i1] = ex + a0;
  }
  if (t == 0) offs[NN] = NT;
}

// ============================ pass A: bin edges by bucket (512 thr) ============================
__global__ __launch_bounds__(512) void k_binA(const int* __restrict__ src, const int* __restrict__ dst,
                                              int* __restrict__ bcur, unsigned int* __restrict__ bpk) {
  __shared__ int hist[NBK];
  __shared__ int hscan[NBK];
  __shared__ int gbase[NBK];
  __shared__ int cnt[NBK];
  __shared__ int ssc[256];
  __shared__ unsigned int staged[TA];
  int t = threadIdx.x;
  int e0 = blockIdx.x * TA;
  for (int i = t; i < NBK; i += 512) { hist[i] = 0; cnt[i] = 0; }
  __syncthreads();
#pragma unroll
  for (int i = 0; i < TA / 512; i++) {
    int e = e0 + t + i * 512;
    if (e < NE) atomicAdd(&hist[dst[e] >> BSH], 1);
  }
  __syncthreads();
  // exclusive scan of hist (2 elems/thread, threads 0..255 active)
  {
    int v0 = 0, v1 = 0, x = 0;
    if (t < 256) {
      v0 = (2 * t < NBK) ? hist[2 * t] : 0;
      v1 = (2 * t + 1 < NBK) ? hist[2 * t + 1] : 0;
      x = v0 + v1;
      ssc[t] = x;
    }
    for (int off = 1; off < 256; off <<= 1) {
      __syncthreads();
      int y = (t >= off && t < 256) ? ssc[t - off] : 0;
      __syncthreads();
      if (t < 256) { x += y; ssc[t] = x; }
    }
    if (t < 256) {
      int ex = x - (v0 + v1);
      if (2 * t < NBK) { hscan[2 * t] = ex; if (v0 > 0) gbase[2 * t] = atomicAdd(&bcur[2 * t], v0); }
      if (2 * t + 1 < NBK) { hscan[2 * t + 1] = ex + v0; if (v1 > 0) gbase[2 * t + 1] = atomicAdd(&bcur[2 * t + 1], v1); }
    }
  }
  __syncthreads();
#pragma unroll
  for (int i = 0; i < TA / 512; i++) {
    int e = e0 + t + i * 512;
    if (e < NE) {
      int d = dst[e];
      int b = d >> BSH;
      int pos = hscan[b] + atomicAdd(&cnt[b], 1);
      staged[pos] = ((unsigned int)src[e] << BSH) | (unsigned int)(d & (BSZ - 1));
    }
  }
  __syncthreads();
  int wave = t >> 6, lane = t & 63;
  for (int b = wave; b < NBK; b += 8) {
    int c = hist[b];
    if (c > 0) {
      int lo = hscan[b], gb = gbase[b];
      for (int j = lane; j < c; j += 64) bpk[gb + j] = staged[lo + j];
    }
  }
}

// ============================ pass B: sort bucket by dst, add self-loops, emit offs + adj ==========
__global__ __launch_bounds__(256) void k_binB(const unsigned int* __restrict__ bpk,
                                              const int* __restrict__ bcnt,
                                              const int* __restrict__ ebase,
                                              const int* __restrict__ abase,
                                              int* __restrict__ offs, int* __restrict__ adj) {
  __shared__ int lhist[BSZ];
  __shared__ int lscan[BSZ];
  __shared__ int lcur[BSZ];
  __shared__ unsigned int staged[CAPB];
  int b = blockIdx.x;
  int t = threadIdx.x;
  int nbeg = b << BSH;
  int nloc = min(BSZ, NN - nbeg);
  int ebeg = ebase[b];
  int ecnt = bcnt[b];
  int aeg = abase[b];
  int total = ecnt + nloc;
  lhist[t] = (t < nloc) ? 1 : 0;   // self-loop occupies slot 0 of each node's segment
  lcur[t] = 1;
  __syncthreads();
  for (int i = t; i < ecnt; i += 256) atomicAdd(&lhist[bpk[ebeg + i] & (BSZ - 1)], 1);
  __syncthreads();
  // exclusive scan of 256
  {
    int v = lhist[t];
    int x = v;
    lscan[t] = x;
    for (int off = 1; off < 256; off <<= 1) {
      __syncthreads();
      int y = (t >= off) ? lscan[t - off] : 0;
      __syncthreads();
      x += y;
      lscan[t] = x;
    }
    __syncthreads();
    lscan[t] = x - v;
  }
  __syncthreads();
  if (t < nloc) {
    offs[nbeg + t] = aeg + lscan[t];
    staged[lscan[t]] = (unsigned int)(nbeg + t);   // self-loop: src = node itself
  }
  __syncthreads();
  for (int i = t; i < ecnt; i += 256) {
    unsigned int v = bpk[ebeg + i];
    int dl = v & (BSZ - 1);
    int idx = lscan[dl] + atomicAdd(&lcur[dl], 1);
    unsigned int s = v >> BSH;
    if (idx < CAPB) staged[idx] = s;
    else adj[aeg + idx] = (int)s;  // statistically never
  }
  __syncthreads();
  int lim = min(total, CAPB);
  for (int i = t; i < lim; i += 256) adj[aeg + i] = (int)staged[i];
}

// ============================ edge weights (flat, thread-per-node) ============================
// wh[e][h] = exp(leaky(asrc[s_e][h] + adst[n][h])) packed f16x4 per edge.
__global__ __launch_bounds__(256) void k_edgew(const int* __restrict__ adj, const int* __restrict__ offs,
                                               const float* __restrict__ asrc, const float* __restrict__ adst,
                                               half_t* __restrict__ wh) {
  int n = blockIdx.x * 256 + threadIdx.x;
  if (n >= NN) return;
  f32x4 ad = *(const f32x4*)(adst + (size_t)n * 4);
  int beg = offs[n], end = offs[n + 1];
  int e = beg;
  for (; e + 1 < end; e += 2) {
    int s0 = adj[e], s1 = adj[e + 1];
    f32x4 a0 = *(const f32x4*)(asrc + (size_t)s0 * 4);
    f32x4 a1 = *(const f32x4*)(asrc + (size_t)s1 * 4);
    f16x4 w0, w1;
#pragma unroll
    for (int h = 0; h < 4; h++) {
      float e0 = a0[h] + ad[h];
      float e1 = a1[h] + ad[h];
      e0 = (e0 > 0.f) ? e0 : 0.2f * e0;
      e1 = (e1 > 0.f) ? e1 : 0.2f * e1;
      w0[h] = (half_t)__expf(e0);
      w1[h] = (half_t)__expf(e1);
    }
    *(f16x4*)(wh + (size_t)e * 4) = w0;
    *(f16x4*)(wh + (size_t)(e + 1) * 4) = w1;
  }
  if (e < end) {
    int s = adj[e];
    f32x4 a0 = *(const f32x4*)(asrc + (size_t)s * 4);
    f16x4 w0;
#pragma unroll
    for (int h = 0; h < 4; h++) {
      float e0 = a0[h] + ad[h];
      e0 = (e0 > 0.f) ? e0 : 0.2f * e0;
      w0[h] = (half_t)__expf(e0);
    }
    *(f16x4*)(wh + (size_t)e * 4) = w0;
  }
}

// ============================ per-node gather aggregation ============================
// one wave per dst node; 16 lanes x half8 per row; 4 groups x 2-unroll = 8 rows in flight;
// softmax denominator accumulated inline (wsum).
__global__ __launch_bounds__(256) void k_aggregate(const half_t* __restrict__ H, const int* __restrict__ offs,
                                                   const int* __restrict__ adj, const half_t* __restrict__ wh,
                                                   const float* __restrict__ bias, half_t* __restrict__ out) {
  int n = blockIdx.x * 4 + (threadIdx.x >> 6);
  if (n >= NN) return;
  int lane = threadIdx.x & 63;
  int l15 = lane & 15, g = lane >> 4;
  int head = l15 >> 2;
  float acc[8] = {0.f, 0.f, 0.f, 0.f, 0.f, 0.f, 0.f, 0.f};
  float wsum = 0.f;
  int beg = offs[n], end = offs[n + 1];
  int i = beg + g;
  while (i + 4 < end) {
    int s0 = adj[i], s1 = adj[i + 4];
    float w0 = (float)wh[(size_t)i * 4 + head];
    float w1 = (float)wh[(size_t)(i + 4) * 4 + head];
    f16x8 h0 = *(const f16x8*)(H + (size_t)s0 * 128 + l15 * 8);
    f16x8 h1 = *(const f16x8*)(H + (size_t)s1 * 128 + l15 * 8);
    wsum += w0 + w1;
#pragma unroll
    for (int j = 0; j < 8; j++) acc[j] += w0 * (float)h0[j] + w1 * (float)h1[j];
    i += 8;
  }
  if (i < end) {
    int s = adj[i];
    float w = (float)wh[(size_t)i * 4 + head];
    f16x8 hv = *(const f16x8*)(H + (size_t)s * 128 + l15 * 8);
    wsum += w;
#pragma unroll
    for (int j = 0; j < 8; j++) acc[j] += w * (float)hv[j];
  }
#pragma unroll
  for (int m = 16; m < 64; m <<= 1) {
    wsum += __shfl_xor(wsum, m, 64);
#pragma unroll
    for (int j = 0; j < 8; j++) acc[j] += __shfl_xor(acc[j], m, 64);
  }
  float scale = 1.0f / (wsum + 1e-16f);
  float o0 = acc[0], o1 = acc[1];
  if (g == 1) { o0 = acc[2]; o1 = acc[3]; }
  if (g == 2) { o0 = acc[4]; o1 = acc[5]; }
  if (g == 3) { o0 = acc[6]; o1 = acc[7]; }
  int ch = l15 * 8 + g * 2;
  o0 = fmaxf(o0 * scale + bias[ch], 0.f);
  o1 = fmaxf(o1 * scale + bias[ch + 1], 0.f);
  f16x2 o;
  o[0] = (half_t)o0;
  o[1] = (half_t)o1;
  *(f16x2*)(out + (size_t)n * 128 + ch) = o;
}

// ============================ MFMA GEMM + attention logits ============================
// H(fp16 node-major) = fp16(X) @ fp16(W); asrc/adst fp32 logits from C-fragments.
template <typename T>
__global__ __launch_bounds__(256) void k_gemm_att(const T* __restrict__ X, const float* __restrict__ W,
                                                  const float* __restrict__ atts, const float* __restrict__ attd,
                                                  half_t* __restrict__ H, float* __restrict__ asrc,
                                                  float* __restrict__ adst) {
  __shared__ __align__(16) half_t Xt[128 * 40];   // [row][k], stride 40 halves
  __shared__ __align__(16) half_t Wt[128 * 40];   // [n][k], stride 40 halves
  int t = threadIdx.x;
  int wave = t >> 6, lane = t & 63;
  int l15 = lane & 15, quad = lane >> 4;
  int rb = blockIdx.x * 128;

  f32x4 acc[2][8];
#pragma unroll
  for (int rt = 0; rt < 2; rt++)
#pragma unroll
    for (int ct = 0; ct < 8; ct++) acc[rt][ct] = (f32x4){0.f, 0.f, 0.f, 0.f};

  for (int k0 = 0; k0 < 128; k0 += 32) {
    __syncthreads();
    if constexpr (sizeof(T) == 4) {
#pragma unroll
      for (int i = 0; i < 4; i++) {
        int lin = i * 256 + t;
        int row = lin >> 3;
        int c4 = (lin & 7) * 4;
        float4 v = make_float4(0.f, 0.f, 0.f, 0.f);
        int gr = rb + row;
        if (gr < NN) v = *(const float4*)((const float*)X + (size_t)gr * 128 + k0 + c4);
        f16x4 hv;
        hv[0] = (half_t)v.x; hv[1] = (half_t)v.y; hv[2] = (half_t)v.z; hv[3] = (half_t)v.w;
        *(f16x4*)(Xt + row * 40 + c4) = hv;
      }
    } else {
#pragma unroll
      for (int i = 0; i < 2; i++) {
        int lin = i * 256 + t;
        int row = lin >> 2;
        int c8 = (lin & 3) * 8;
        f16x8 hv = (f16x8)(half_t)0;
        int gr = rb + row;
        if (gr < NN) hv = *(const f16x8*)((const half_t*)X + (size_t)gr * 128 + k0 + c8);
        *(f16x8*)(Xt + row * 40 + c8) = hv;
      }
    }
#pragma unroll
    for (int i = 0; i < 4; i++) {
      int lin = i * 256 + t;
      int kr = lin >> 5;
      int n4 = (lin & 31) * 4;
      float4 v = *(const float4*)(W + (size_t)(k0 + kr) * 128 + n4);
      Wt[(n4 + 0) * 40 + kr] = (half_t)v.x;
      Wt[(n4 + 1) * 40 + kr] = (half_t)v.y;
      Wt[(n4 + 2) * 40 + kr] = (half_t)v.z;
      Wt[(n4 + 3) * 40 + kr] = (half_t)v.w;
    }
    __syncthreads();

    f16x8 a0 = *(const f16x8*)(Xt + (wave * 32 + l15) * 40 + quad * 8);
    f16x8 a1 = *(const f16x8*)(Xt + (wave * 32 + 16 + l15) * 40 + quad * 8);
#pragma unroll
    for (int ct = 0; ct < 8; ct++) {
      f16x8 b = *(const f16x8*)(Wt + (ct * 16 + l15) * 40 + quad * 8);
      acc[0][ct] = __builtin_amdgcn_mfma_f32_16x16x32_f16(a0, b, acc[0][ct], 0, 0, 0);
      acc[1][ct] = __builtin_amdgcn_mfma_f32_16x16x32_f16(a1, b, acc[1][ct], 0, 0, 0);
    }
  }

  // ---- store H node-major fp16 ----
#pragma unroll
  for (int rt = 0; rt < 2; rt++) {
    int rbase = rb + wave * 32 + rt * 16 + quad * 4;
#pragma unroll
    for (int reg = 0; reg < 4; reg++) {
      int row = rbase + reg;
      if (row < NN) {
#pragma unroll
        for (int ct = 0; ct < 8; ct++) {
          H[(size_t)row * 128 + ct * 16 + l15] = (half_t)acc[rt][ct][reg];
        }
      }
    }
  }

  // ---- attention logits ----
  float s_lo[4], s_hi[4], d_lo[4], d_hi[4];
#pragma unroll
  for (int h = 0; h < 4; h++) {
    s_lo[h] = atts[h * 32 + l15];
    s_hi[h] = atts[h * 32 + 16 + l15];
    d_lo[h] = attd[h * 32 + l15];
    d_hi[h] = attd[h * 32 + 16 + l15];
  }
#pragma unroll
  for (int rt = 0; rt < 2; rt++) {
    float ps[4][4], pd[4][4];  // [reg][head]
#pragma unroll
    for (int reg = 0; reg < 4; reg++)
#pragma unroll
      for (int h = 0; h < 4; h++) {
        ps[reg][h] = acc[rt][2 * h][reg] * s_lo[h] + acc[rt][2 * h + 1][reg] * s_hi[h];
        pd[reg][h] = acc[rt][2 * h][reg] * d_lo[h] + acc[rt][2 * h + 1][reg] * d_hi[h];
      }
#pragma unroll
    for (int m = 1; m < 16; m <<= 1) {
#pragma unroll
      for (int reg = 0; reg < 4; reg++)
#pragma unroll
        for (int h = 0; h < 4; h++) {
          ps[reg][h] += __shfl_xor(ps[reg][h], m, 64);
          pd[reg][h] += __shfl_xor(pd[reg][h], m, 64);
        }
    }
    float vs = 0.f, vd = 0.f;
#pragma unroll
    for (int reg = 0; reg < 4; reg++)
#pragma unroll
      for (int h = 0; h < 4; h++) {
        if (l15 == reg * 4 + h) { vs = ps[reg][h]; vd = pd[reg][h]; }
      }
    int row = rb + wave * 32 + rt * 16 + quad * 4 + (l15 >> 2);
    int h = l15 & 3;
    if (row < NN) {
      asrc[row * 4 + h] = vs;
      adst[row * 4 + h] = vd;
    }
  }
}

// ============================ classifier (MFMA, N=40 padded to 48) ============================
__global__ __launch_bounds__(256) void k_classifier(const half_t* __restrict__ Hf, const float* __restrict__ Wc,
                                                    const float* __restrict__ bc, float* __restrict__ out) {
  __shared__ __align__(16) half_t Xt[128 * 40];
  __shared__ __align__(16) half_t Wt[48 * 40];
  int t = threadIdx.x;
  int wave = t >> 6, lane = t & 63;
  int l15 = lane & 15, quad = lane >> 4;
  int rb = blockIdx.x * 128;

  f32x4 acc[2][3];
#pragma unroll
  for (int rt = 0; rt < 2; rt++)
#pragma unroll
    for (int ct = 0; ct < 3; ct++) acc[rt][ct] = (f32x4){0.f, 0.f, 0.f, 0.f};

  for (int k0 = 0; k0 < 128; k0 += 32) {
    __syncthreads();
#pragma unroll
    for (int i = 0; i < 2; i++) {
      int lin = i * 256 + t;
      int row = lin >> 2;
      int c8 = (lin & 3) * 8;
      f16x8 hv = (f16x8)(half_t)0;
      int gr = rb + row;
      if (gr < NN) hv = *(const f16x8*)(Hf + (size_t)gr * 128 + k0 + c8);
      *(f16x8*)(Xt + row * 40 + c8) = hv;
    }
#pragma unroll
    for (int i = 0; i < 6; i++) {
      int lin = i * 256 + t;
      int kr = lin / 48;
      int n = lin - kr * 48;
      Wt[n * 40 + kr] = (n < 40) ? (half_t)Wc[(size_t)(k0 + kr) * 40 + n] : (half_t)0;
    }
    __syncthreads();

    f16x8 a0 = *(const f16x8*)(Xt + (wave * 32 + l15) * 40 + quad * 8);
    f16x8 a1 = *(const f16x8*)(Xt + (wave * 32 + 16 + l15) * 40 + quad * 8);
#pragma unroll
    for (int ct = 0; ct < 3; ct++) {
      f16x8 b = *(const f16x8*)(Wt + (ct * 16 + l15) * 40 + quad * 8);
      acc[0][ct] = __builtin_amdgcn_mfma_f32_16x16x32_f16(a0, b, acc[0][ct], 0, 0, 0);
      acc[1][ct] = __builtin_amdgcn_mfma_f32_16x16x32_f16(a1, b, acc[1][ct], 0, 0, 0);
    }
  }

#pragma unroll
  for (int rt = 0; rt < 2; rt++) {
#pragma unroll
    for (int ct = 0; ct < 3; ct++) {
      int col = ct * 16 + l15;
      if (col < 40) {
        float bv = bc[col];
#pragma unroll
        for (int reg = 0; reg < 4; reg++) {
          int row = rb + wave * 32 + rt * 16 + quad * 4 + reg;
          if (row < NN) out[(size_t)row * 40 + col] = acc[rt][ct][reg] + bv;
        }
      }
    }
  }
}

// ============================ launch ============================

extern "C" void kernel_launch(void* const* d_in, const int* in_sizes, int n_in,
                              void* d_out, int out_size, void* d_ws, size_t ws_size,
                              hipStream_t stream) {
  const float* x   = (const float*)d_in[0];
  const int*   ei  = (const int*)d_in[1];
  const float* W1  = (const float*)d_in[2];
  const float* as1 = (const float*)d_in[3];
  const float* ad1 = (const float*)d_in[4];
  const float* b1  = (const float*)d_in[5];
  const float* W2  = (const float*)d_in[6];
  const float* as2 = (const float*)d_in[7];
  const float* ad2 = (const float*)d_in[8];
  const float* b2  = (const float*)d_in[9];
  const float* Wc  = (const float*)d_in[10];
  const float* bc  = (const float*)d_in[11];
  float* out = (float*)d_out;

  const int* esrc = ei;
  const int* edst = ei + NE;

  char* w = (char*)d_ws;
  auto alloc = [&](size_t bytes) {
    void* p = (void*)w;
    w += (bytes + 255) & ~(size_t)255;
    return p;
  };
  half_t* A   = (half_t*)alloc(sizeof(half_t) * (size_t)NN * 128);  // node-major gather target
  half_t* B   = (half_t*)alloc(sizeof(half_t) * (size_t)NN * 128);  // node-major layer output
  float* asrc = (float*)alloc(sizeof(float) * (size_t)NN * 4);
  float* adst = (float*)alloc(sizeof(float) * (size_t)NN * 4);
  int* offs   = (int*)alloc(sizeof(int) * (NN + 1));
  unsigned int* bpk = (unsigned int*)alloc(sizeof(unsigned int) * NE);
  int* adj    = (int*)alloc(sizeof(int) * NT);
  half_t* wh  = (half_t*)alloc(sizeof(half_t) * (size_t)NT * 4);
  int* bcnt   = (int*)alloc(sizeof(int) * NBK);
  int* ebase  = (int*)alloc(sizeof(int) * NBK);
  int* abase  = (int*)alloc(sizeof(int) * NBK);
  int* bcur   = (int*)alloc(sizeof(int) * NBK);

  // ---- CSR build (self-loops folded in) ----
  k_zero<<<(NBK + 255) / 256, 256, 0, stream>>>(bcnt, NBK);
  k_bhist<<<NBH, 256, 0, stream>>>(edst, bcnt);
  k_bscan<<<1, 256, 0, stream>>>(bcnt, ebase, abase, bcur, offs);
  k_binA<<<NBA, 512, 0, stream>>>(esrc, edst, bcur, bpk);
  k_binB<<<NBK, 256, 0, stream>>>(bpk, bcnt, ebase, abase, offs, adj);

  // ---- layer 1 ----
  k_gemm_att<float><<<(NN + 127) / 128, 256, 0, stream>>>(x, W1, as1, ad1, A, asrc, adst);
  k_edgew<<<(NN + 255) / 256, 256, 0, stream>>>(adj, offs, asrc, adst, wh);
  k_aggregate<<<(NN + 3) / 4, 256, 0, stream>>>(A, offs, adj, wh, b1, B);

  // ---- layer 2 ----
  k_gemm_att<half_t><<<(NN + 127) / 128, 256, 0, stream>>>(B, W2, as2, ad2, A, asrc, adst);
  k_edgew<<<(NN + 255) / 256, 256, 0, stream>>>(adj, offs, asrc, adst, wh);
  k_aggregate<<<(NN + 3) / 4, 256, 0, stream>>>(A, offs, adj, wh, b2, B);

  // ---- classifier ----
  k_classifier<<<(NN + 127) / 128, 256, 0, stream>>>(B, Wc, bc, out);
}